// Round 5
// baseline (25636.353 us; speedup 1.0000x reference)
//
#include <hip/hip_runtime.h>
#include <math.h>

#define B_    32
#define S_    2048
#define DIN   256
#define H_    512
#define G_    2048
#define DOUT  256

#define NBLK   136
#define NPHASE 2050

typedef __attribute__((ext_vector_type(8))) short bf16x8;
typedef __attribute__((ext_vector_type(16))) float f32x16;

#define MFMA32(a,b,c) __builtin_amdgcn_mfma_f32_32x32x16_bf16((a),(b),(c),0,0,0)

// ---- ws byte offsets ----
#define OB_CTR       0u          // phase counters, 64B stride
#define OB_H0HI      147456u     // bf16 [2][32][512] per buffer
#define OB_H0LO      212992u
#define OB_H1HI      278528u
#define OB_H1LO      344064u
#define OB_STATE_END 409600u
#define OB_B0        409600u     // fp32 [2048] combined bias (packed cols)
#define OB_B1        417792u
#define OB_FHI       425984u     // bf16 [256][512]  Wfc^T split
#define OB_FLO       688128u
#define OB_W0HI      950272u     // bf16 [2048][768]  packed-col-major split
#define OB_W0LO      4096000u
#define OB_W1HI      7241728u    // bf16 [2048][1024]
#define OB_W1LO      11436032u
#define OB_END       15630336u

// ---- dynamic LDS layout (bytes) ----
#define LS_WHI   0
#define LS_WLO   65536
#define LS_PT    131072          // float[4][32][32]
#define LS_CST   147456          // float[256]
#define LS_TOTAL 148480

__device__ __forceinline__ float sigf(float v) { return 1.0f / (1.0f + expf(-v)); }

__device__ __forceinline__ unsigned short f2b(float f) {   // fp32 -> bf16 RNE
    union { float f; unsigned u; } v; v.f = f;
    unsigned r = v.u + 0x7fffu + ((v.u >> 16) & 1u);
    return (unsigned short)(r >> 16);
}
__device__ __forceinline__ float b2f(unsigned short h) {
    union { unsigned u; float f; } v; v.u = ((unsigned)h) << 16; return v.f;
}

// ---- repack: W -> packed-col-major split bf16 ----
__global__ __launch_bounds__(256) void repack_w(
    const float* __restrict__ s1, const float* __restrict__ s2,
    int k1, int K, int srcld, int dopack,
    unsigned short* __restrict__ hi, unsigned short* __restrict__ lo)
{
    const int p  = blockIdx.x;
    const int kk = blockIdx.y * 256 + threadIdx.x;
    if (kk >= K) return;
    const int oc = dopack ? ((((p >> 2) & 3) * H_) + ((p >> 4) << 2) + (p & 3)) : p;
    const float w = (kk < k1) ? s1[(size_t)kk * srcld + oc]
                              : s2[(size_t)(kk - k1) * srcld + oc];
    const unsigned short h = f2b(w);
    hi[(size_t)p * K + kk] = h;
    lo[(size_t)p * K + kk] = f2b(w - b2f(h));
}

__global__ __launch_bounds__(256) void repack_bias(
    const float* __restrict__ bx0, const float* __restrict__ bh0,
    const float* __restrict__ bx1, const float* __restrict__ bh1,
    char* __restrict__ wsb)
{
    const int q = blockIdx.x * 256 + threadIdx.x;
    if (q >= 2 * G_) return;
    const int p  = q & (G_ - 1);
    const int oc = (((p >> 2) & 3) * H_) + ((p >> 4) << 2) + (p & 3);
    float* dst = (float*)(wsb + (q < G_ ? OB_B0 : OB_B1));
    dst[p] = (q < G_) ? (bx0[oc] + bh0[oc]) : (bx1[oc] + bh1[oc]);
}

// ---- persistent pipeline kernel ----
// blocks [0,64): layer0 t=p; [64,128): layer1 t=p-1; [128,136): FC t=p-2
__global__ __launch_bounds__(512, 2) void lstm_persist(
    const float* __restrict__ x, const float* __restrict__ bfc,
    float* __restrict__ out, char* __restrict__ wsb)
{
    extern __shared__ char smem[];
    unsigned short* Whi = (unsigned short*)(smem + LS_WHI);
    unsigned short* Wlo = (unsigned short*)(smem + LS_WLO);
    float* Pt   = (float*)(smem + LS_PT);
    float* cstL = (float*)(smem + LS_CST);
    unsigned* ctr = (unsigned*)wsb;

    const int blk = blockIdx.x, tid = threadIdx.x;
    const int wave = tid >> 6, lane = tid & 63;
    const int colc = lane & 31, halfl = lane >> 5;

    int role, bb;
    if (blk < 64)       { role = 0; bb = blk; }
    else if (blk < 128) { role = 1; bb = blk - 64; }
    else                { role = 2; bb = blk - 128; }

    const int K  = (role == 0) ? 768 : (role == 1 ? 1024 : 512);
    const int p0 = bb * 32;

    const unsigned short *WHIg, *WLOg;
    if (role == 0)      { WHIg = (const unsigned short*)(wsb + OB_W0HI); WLOg = (const unsigned short*)(wsb + OB_W0LO); }
    else if (role == 1) { WHIg = (const unsigned short*)(wsb + OB_W1HI); WLOg = (const unsigned short*)(wsb + OB_W1LO); }
    else                { WHIg = (const unsigned short*)(wsb + OB_FHI);  WLOg = (const unsigned short*)(wsb + OB_FLO); }

    // stage this block's weight slice into LDS once: [k8][32 cols][8]
    const int nk8 = K >> 3;
    for (int idx = tid; idx < nk8 * 32; idx += 512) {
        const int k8 = idx >> 5, cl = idx & 31;
        *(bf16x8*)(Whi + idx * 8) = *(const bf16x8*)(WHIg + (size_t)(p0 + cl) * K + k8 * 8);
        *(bf16x8*)(Wlo + idx * 8) = *(const bf16x8*)(WLOg + (size_t)(p0 + cl) * K + k8 * 8);
    }
    for (int i = tid; i < 256; i += 512) cstL[i] = 0.f;
    __syncthreads();

    unsigned short* H0HI = (unsigned short*)(wsb + OB_H0HI);
    unsigned short* H0LO = (unsigned short*)(wsb + OB_H0LO);
    unsigned short* H1HI = (unsigned short*)(wsb + OB_H1HI);
    unsigned short* H1LO = (unsigned short*)(wsb + OB_H1LO);
    const float* Bp = (const float*)(wsb + (role == 1 ? OB_B1 : OB_B0));

    const int k0    = wave * (K >> 3);
    const int nstep = K >> 7;        // k16 steps per wave: 6 / 8 / 4

    for (int p = 0; p < NPHASE; ++p) {
        const int t = (role == 0) ? p : (role == 1 ? p - 1 : p - 2);
        if (t >= 0 && t < S_) {
            const int par_t = t & 1, par_tm = (t + 1) & 1;
            const unsigned short *A0hi = 0, *A0lo = 0, *A1hi = 0, *A1lo = 0;
            if (role == 0)      { A1hi = H0HI + par_tm * 16384; A1lo = H0LO + par_tm * 16384; }
            else if (role == 1) { A0hi = H0HI + par_t  * 16384; A0lo = H0LO + par_t  * 16384;
                                  A1hi = H1HI + par_tm * 16384; A1lo = H1LO + par_tm * 16384; }
            else                { A0hi = H1HI + par_t  * 16384; A0lo = H1LO + par_t  * 16384; }

            auto LOADA = [&](int kf, bf16x8& ah, bf16x8& al) {
                if (role == 0 && kf < 256) {
                    const float* xp = x + ((size_t)colc * S_ + t) * DIN + kf + halfl * 8;
                    #pragma unroll
                    for (int j = 0; j < 8; ++j) {
                        const float v = xp[j];
                        const unsigned short hh2 = f2b(v);
                        ah[j] = (short)hh2; al[j] = (short)f2b(v - b2f(hh2));
                    }
                } else if (role == 0) {
                    const int off = colc * 512 + (kf - 256) + halfl * 8;
                    ah = *(const bf16x8*)(A1hi + off); al = *(const bf16x8*)(A1lo + off);
                } else if (role == 1 && kf < 512) {
                    const int off = colc * 512 + kf + halfl * 8;
                    ah = *(const bf16x8*)(A0hi + off); al = *(const bf16x8*)(A0lo + off);
                } else if (role == 1) {
                    const int off = colc * 512 + (kf - 512) + halfl * 8;
                    ah = *(const bf16x8*)(A1hi + off); al = *(const bf16x8*)(A1lo + off);
                } else {
                    const int off = colc * 512 + kf + halfl * 8;
                    ah = *(const bf16x8*)(A0hi + off); al = *(const bf16x8*)(A0lo + off);
                }
            };

            f32x16 acc;
            #pragma unroll
            for (int i = 0; i < 16; ++i) acc[i] = 0.f;

            bf16x8 ah, al;
            LOADA(k0, ah, al);
            for (int s = 0; s < nstep; ++s) {
                bf16x8 nah, nal;
                if (s + 1 < nstep) LOADA(k0 + (s + 1) * 16, nah, nal);
                const int k8a = ((k0 + s * 16) >> 3) + halfl;
                const bf16x8 bh = *(const bf16x8*)(Whi + (k8a * 32 + colc) * 8);
                const bf16x8 bl = *(const bf16x8*)(Wlo + (k8a * 32 + colc) * 8);
                acc = MFMA32(ah, bh, acc);
                acc = MFMA32(al, bh, acc);
                acc = MFMA32(ah, bl, acc);
                ah = nah; al = nal;
            }

            // cross-wave reduce: waves 4-7 store, waves 0-3 accumulate
            if (wave >= 4) {
                #pragma unroll
                for (int rg = 0; rg < 16; ++rg) {
                    const int row = (rg & 3) + 8 * (rg >> 2) + 4 * halfl;
                    Pt[(wave - 4) * 1024 + row * 32 + colc] = acc[rg];
                }
            }
            __syncthreads();
            if (wave < 4) {
                #pragma unroll
                for (int rg = 0; rg < 16; ++rg) {
                    const int row = (rg & 3) + 8 * (rg >> 2) + 4 * halfl;
                    Pt[wave * 1024 + row * 32 + colc] += acc[rg];
                }
            }
            __syncthreads();

            if (role == 2) {
                #pragma unroll
                for (int ii = 0; ii < 2; ++ii) {
                    const int idx = tid * 2 + ii;
                    const int r = idx >> 5, c = idx & 31;
                    const float v = Pt[idx] + Pt[1024 + idx] + Pt[2048 + idx] + Pt[3072 + idx]
                                  + bfc[p0 + c];
                    out[((size_t)r * S_ + t) * DOUT + p0 + c] = v;
                }
            } else {
                #pragma unroll
                for (int ii = 0; ii < 2; ++ii) {
                    const int idx = tid * 2 + ii;
                    Pt[idx] = Pt[idx] + Pt[1024 + idx] + Pt[2048 + idx] + Pt[3072 + idx]
                            + Bp[p0 + (idx & 31)];
                }
                __syncthreads();
                if (tid < 256) {
                    const int r = tid >> 3, lu = tid & 7;
                    const int cb = (lu >> 2) * 16 + (lu & 3);
                    const float fg = Pt[r * 32 + cb + 0];
                    const float ig = Pt[r * 32 + cb + 4];
                    const float gg = Pt[r * 32 + cb + 8];
                    const float og = Pt[r * 32 + cb + 12];
                    const float cv = cstL[tid];
                    const float cn = sigf(fg) * cv + sigf(ig) * tanhf(gg);
                    const float hn = sigf(og) * tanhf(cn);
                    cstL[tid] = cn;
                    const unsigned short hh2 = f2b(hn);
                    const unsigned short hl2 = f2b(hn - b2f(hh2));
                    const int off = par_t * 16384 + r * 512 + bb * 8 + lu;
                    if (role == 0) { H0HI[off] = hh2; H0LO[off] = hl2; }
                    else           { H1HI[off] = hh2; H1LO[off] = hl2; }
                }
            }
        }

        if (p < NPHASE - 1) {
            __syncthreads();
            if (tid == 0) {
                __builtin_amdgcn_fence(__ATOMIC_RELEASE, "agent");
                __hip_atomic_fetch_add(&ctr[p * 16], 1u, __ATOMIC_RELAXED, __HIP_MEMORY_SCOPE_AGENT);
                while (__hip_atomic_load(&ctr[p * 16], __ATOMIC_RELAXED, __HIP_MEMORY_SCOPE_AGENT)
                       < (unsigned)NBLK)
                    __builtin_amdgcn_s_sleep(4);
                __builtin_amdgcn_fence(__ATOMIC_ACQUIRE, "agent");
            }
            __syncthreads();
        }
    }
}

extern "C" void kernel_launch(void* const* d_in, const int* in_sizes, int n_in,
                              void* d_out, int out_size, void* d_ws, size_t ws_size,
                              hipStream_t stream)
{
    const float* x   = (const float*)d_in[0];
    const float* Wx0 = (const float*)d_in[1];
    const float* bx0 = (const float*)d_in[2];
    const float* Wh0 = (const float*)d_in[3];
    const float* bh0 = (const float*)d_in[4];
    const float* Wx1 = (const float*)d_in[5];
    const float* bx1 = (const float*)d_in[6];
    const float* Wh1 = (const float*)d_in[7];
    const float* bh1 = (const float*)d_in[8];
    const float* Wfc = (const float*)d_in[9];
    const float* bfc = (const float*)d_in[10];
    float* out = (float*)d_out;
    char*  wsb = (char*)d_ws;

    // zero barrier counters + h state (runs inside the graph every replay)
    hipMemsetAsync(d_ws, 0, OB_STATE_END, stream);

    repack_w<<<dim3(G_, 3), 256, 0, stream>>>(Wx0, Wh0, 256, 768, G_, 1,
        (unsigned short*)(wsb + OB_W0HI), (unsigned short*)(wsb + OB_W0LO));
    repack_w<<<dim3(G_, 4), 256, 0, stream>>>(Wx1, Wh1, 512, 1024, G_, 1,
        (unsigned short*)(wsb + OB_W1HI), (unsigned short*)(wsb + OB_W1LO));
    repack_w<<<dim3(DOUT, 2), 256, 0, stream>>>(Wfc, Wfc, 512, 512, DOUT, 0,
        (unsigned short*)(wsb + OB_FHI), (unsigned short*)(wsb + OB_FLO));
    repack_bias<<<16, 256, 0, stream>>>(bx0, bh0, bx1, bh1, wsb);

    hipFuncSetAttribute((const void*)lstm_persist,
                        hipFuncAttributeMaxDynamicSharedMemorySize, LS_TOTAL);
    lstm_persist<<<NBLK, 512, LS_TOTAL, stream>>>(x, bfc, out, wsb);
}